// Round 1
// baseline (151.316 us; speedup 1.0000x reference)
//
#include <hip/hip_runtime.h>
#include <stdint.h>

// ContrastiveLossInBatch: loss = mean_i [ lse_j(q_i.k_j/T) - q_i.k_i/T ],
// N=8192, C=256, T=0.07. Fused f16-MFMA GEMM + online logsumexp (base-2).
//
// Workspace layout (needs 8 MiB + 768 KiB):
//   [0,       4 MiB)  q in f16, pre-scaled by (1/T)*log2(e)
//   [4 MiB,   8 MiB)  k in f16
//   [8 MiB, +256 KiB) per-(split,row) running max M   (SPLIT*N floats)
//   ...               per-(split,row) running sum S
//   ...               per-(split,row) diagonal  P

#define N_ROWS 8192
#define C_DIM  256
#define BM     64
#define BN     64
#define SPLIT  8
#define JCOLS  (N_ROWS / SPLIT)   // 1024 columns per split
#define JTILES (JCOLS / BN)       // 16 k-tiles per split

typedef __attribute__((ext_vector_type(8))) _Float16 half8;
typedef __attribute__((ext_vector_type(4))) _Float16 half4;
typedef __attribute__((ext_vector_type(4))) float    f32x4;

__device__ __forceinline__ void gload_lds16(const void* g, void* l) {
  __builtin_amdgcn_global_load_lds(
      (const __attribute__((address_space(1))) unsigned int*)g,
      (__attribute__((address_space(3))) unsigned int*)l, 16, 0, 0);
}

// ---- fp32 -> f16 conversion; q gets (1/0.07)*log2(e) folded in -------------
__global__ void cvt_kernel(const float* __restrict__ q, const float* __restrict__ k,
                           _Float16* __restrict__ qh, _Float16* __restrict__ kh) {
  const float QS = 20.60992915555663f;  // (1/0.07) * log2(e)
  int i = blockIdx.x * 256 + threadIdx.x;
  float4 qv = ((const float4*)q)[i];
  float4 kv = ((const float4*)k)[i];
  half4 qo, ko;
  qo[0] = (_Float16)(qv.x * QS); qo[1] = (_Float16)(qv.y * QS);
  qo[2] = (_Float16)(qv.z * QS); qo[3] = (_Float16)(qv.w * QS);
  ko[0] = (_Float16)kv.x; ko[1] = (_Float16)kv.y;
  ko[2] = (_Float16)kv.z; ko[3] = (_Float16)kv.w;
  ((half4*)qh)[i] = qo;
  ((half4*)kh)[i] = ko;
}

// ---- main fused GEMM + online base-2 logsumexp -----------------------------
// Block: 256 threads = 4 waves; wave w owns 16 rows. A-fragments (q) live in
// registers for the whole kernel (C=256 -> 8 frags = 32 VGPRs/lane).
// k-tile (64x256 f16 = 32 KiB, contiguous in global) staged to LDS with
// global_load_lds; 16B chunks XOR-swizzled by row to kill bank conflicts.
__launch_bounds__(256, 4)
__global__ void sim_lse_kernel(const _Float16* __restrict__ qh,
                               const _Float16* __restrict__ kh,
                               float* __restrict__ pM,
                               float* __restrict__ pS,
                               float* __restrict__ pP) {
  __shared__ __align__(16) _Float16 kt[BN * C_DIM];  // 32 KiB
  const int tid  = threadIdx.x;
  const int lane = tid & 63;
  const int wave = tid >> 6;
  const int l15  = lane & 15;
  const int lg   = lane >> 4;       // quad group 0..3

  const int rb   = blockIdx.x;      // row block 0..127
  const int sp   = blockIdx.y;      // column split 0..7
  const int row0 = rb * BM + wave * 16;

  // A fragments: lane holds q[row0+l15][f*32 + lg*8 .. +8)
  half8 afrag[8];
  {
    const _Float16* qr = qh + (size_t)(row0 + l15) * C_DIM + lg * 8;
#pragma unroll
    for (int f = 0; f < 8; ++f)
      afrag[f] = *(const half8*)(qr + f * 32);
  }

  float M[4], S[4], P[4];
#pragma unroll
  for (int r = 0; r < 4; ++r) { M[r] = -__builtin_inff(); S[r] = 0.f; P[r] = -__builtin_inff(); }

  // swizzled LDS base per col-frag: addr = bbase[cf] ^ (ks*64)
  int bbase[4];
#pragma unroll
  for (int cf = 0; cf < 4; ++cf) {
    int nl = cf * 16 + l15;
    bbase[cf] = nl * 512 + (((nl & 31) * 16) ^ (lg * 16));
  }

  const char* ksrc = (const char*)(kh + (size_t)sp * JCOLS * C_DIM);
  char* lds = (char*)kt;

  for (int jt = 0; jt < JTILES; ++jt) {
    // ---- stage k rows [j0, j0+64) : contiguous 32 KiB, swizzled dest ------
    const char* src = ksrc + (size_t)jt * (BN * C_DIM * 2);
#pragma unroll
    for (int it = 0; it < 8; ++it) {
      int linear = it * 4096 + tid * 16;
      int row = linear >> 9;          // 512 B per k row
      int c16 = (linear >> 4) & 31;   // 16B chunk within row
      int gc  = c16 ^ (row & 31);     // LDS(row,c) holds global(row, c^row)
      gload_lds16(src + row * 512 + gc * 16, lds + linear);
    }
    __syncthreads();

    // ---- 64x64 tile: 8 K-steps x 4 col-frags of 16x16x32 MFMA -------------
    f32x4 acc[4];
#pragma unroll
    for (int cf = 0; cf < 4; ++cf) { f32x4 z = {0.f, 0.f, 0.f, 0.f}; acc[cf] = z; }

#pragma unroll
    for (int ks = 0; ks < 8; ++ks) {
#pragma unroll
      for (int cf = 0; cf < 4; ++cf) {
        half8 b = *(const half8*)(lds + (bbase[cf] ^ (ks * 64)));
        acc[cf] = __builtin_amdgcn_mfma_f32_16x16x32_f16(afrag[ks], b, acc[cf], 0, 0, 0);
      }
    }
    __syncthreads();  // all waves done reading before next staging

    const int j0 = sp * JCOLS + jt * BN;

    // ---- diagonal capture (wave-uniform branch; at most 1 tile/split) -----
    if (row0 >= j0 && row0 < j0 + BN) {
#pragma unroll
      for (int r = 0; r < 4; ++r) {
        int d = row0 - j0 + lg * 4 + r;       // tile-local column of diagonal
        float pv = -__builtin_inff();
#pragma unroll
        for (int cf = 0; cf < 4; ++cf)
          if ((d >> 4) == cf && l15 == (d & 15)) pv = acc[cf][r];
#pragma unroll
        for (int off = 1; off < 16; off <<= 1)
          pv = fmaxf(pv, __shfl_xor(pv, off));
        P[r] = pv;
      }
    }

    // ---- online logsumexp (base 2): row = row0 + lg*4 + r -----------------
#pragma unroll
    for (int r = 0; r < 4; ++r) {
      float v0 = acc[0][r], v1 = acc[1][r], v2 = acc[2][r], v3 = acc[3][r];
      float tmax = fmaxf(fmaxf(v0, v1), fmaxf(v2, v3));
#pragma unroll
      for (int off = 1; off < 16; off <<= 1)
        tmax = fmaxf(tmax, __shfl_xor(tmax, off));
      float newM  = fmaxf(M[r], tmax);
      float alpha = exp2f(M[r] - newM);       // exp2(-inf)=0 handles init
      float p = exp2f(v0 - newM) + exp2f(v1 - newM) +
                exp2f(v2 - newM) + exp2f(v3 - newM);
#pragma unroll
      for (int off = 1; off < 16; off <<= 1)
        p += __shfl_xor(p, off);
      S[r] = S[r] * alpha + p;
      M[r] = newM;
    }
  }

  if (l15 == 0) {
#pragma unroll
    for (int r = 0; r < 4; ++r) {
      int grow = row0 + lg * 4 + r;
      pM[(size_t)sp * N_ROWS + grow] = M[r];
      pS[(size_t)sp * N_ROWS + grow] = S[r];
      pP[(size_t)sp * N_ROWS + grow] = P[r];
    }
  }
}

// ---- merge splits per row, convert base-2 -> nats, mean --------------------
__global__ void finish_kernel(const float* __restrict__ pM, const float* __restrict__ pS,
                              const float* __restrict__ pP, float* __restrict__ out) {
  const int tid = threadIdx.x;
  float accl = 0.f;
  for (int r = tid; r < N_ROWS; r += 256) {
    float m = -__builtin_inff();
#pragma unroll
    for (int s = 0; s < SPLIT; ++s) m = fmaxf(m, pM[s * N_ROWS + r]);
    float ssum = 0.f;
    float pos  = -__builtin_inff();
#pragma unroll
    for (int s = 0; s < SPLIT; ++s) {
      ssum += pS[s * N_ROWS + r] * exp2f(pM[s * N_ROWS + r] - m);
      pos = fmaxf(pos, pP[s * N_ROWS + r]);
    }
    accl += (m + log2f(ssum)) - pos;   // row loss in base-2 units
  }
#pragma unroll
  for (int off = 1; off < 64; off <<= 1) accl += __shfl_xor(accl, off);
  __shared__ float wsum[4];
  if ((tid & 63) == 0) wsum[tid >> 6] = accl;
  __syncthreads();
  if (tid == 0) {
    float t = wsum[0] + wsum[1] + wsum[2] + wsum[3];
    out[0] = t * (0.69314718055994531f / (float)N_ROWS);  // ln2 * mean
  }
}

extern "C" void kernel_launch(void* const* d_in, const int* in_sizes, int n_in,
                              void* d_out, int out_size, void* d_ws, size_t ws_size,
                              hipStream_t stream) {
  const float* q = (const float*)d_in[0];
  const float* k = (const float*)d_in[1];
  float* out = (float*)d_out;
  char* ws = (char*)d_ws;

  _Float16* qh = (_Float16*)ws;                                  // 4 MiB
  _Float16* kh = (_Float16*)(ws + (size_t)N_ROWS * C_DIM * 2);   // 4 MiB
  float* pM = (float*)(ws + (size_t)N_ROWS * C_DIM * 4);         // 256 KiB each
  float* pS = pM + SPLIT * N_ROWS;
  float* pP = pS + SPLIT * N_ROWS;

  cvt_kernel<<<dim3(N_ROWS * C_DIM / 4 / 256), dim3(256), 0, stream>>>(q, k, qh, kh);
  sim_lse_kernel<<<dim3(N_ROWS / BM, SPLIT), dim3(256), 0, stream>>>(qh, kh, pM, pS, pP);
  finish_kernel<<<dim3(1), dim3(256), 0, stream>>>(pM, pS, pP, out);
}

// Round 2
// 112.485 us; speedup vs baseline: 1.3452x; 1.3452x over previous
//
#include <hip/hip_runtime.h>
#include <stdint.h>

// ContrastiveLossInBatch: loss = mean_i [ lse_j(q_i.k_j/T) - q_i.k_i/T ],
// N=8192, C=256, T=0.07. Fused f16-MFMA GEMM + per-lane online logsumexp
// (base-2); cross-lane merge happens ONCE at kernel end, not per tile.
//
// Workspace layout (8 MiB + 768 KiB + 128 B):
//   [0,       4 MiB)  q in f16, pre-scaled by (1/T)*log2(e)
//   [4 MiB,   8 MiB)  k in f16
//   [8 MiB, +256 KiB) per-(split,row) running max M   (SPLIT*N floats)
//   ...               per-(split,row) running sum S
//   ...               per-(split,row) diagonal  P
//   ...               32 partial row-loss sums

#define N_ROWS 8192
#define C_DIM  256
#define BM     64
#define BN     64
#define SPLIT  8
#define JCOLS  (N_ROWS / SPLIT)   // 1024 columns per split
#define JTILES (JCOLS / BN)       // 16 k-tiles per split

typedef __attribute__((ext_vector_type(8))) _Float16 half8;
typedef __attribute__((ext_vector_type(4))) _Float16 half4;
typedef __attribute__((ext_vector_type(4))) float    f32x4;

#if __has_builtin(__builtin_amdgcn_exp2f)
#define EXP2(x) __builtin_amdgcn_exp2f(x)
#else
#define EXP2(x) exp2f(x)
#endif
#if __has_builtin(__builtin_amdgcn_logf)
#define LOG2(x) __builtin_amdgcn_logf(x)
#else
#define LOG2(x) log2f(x)
#endif

__device__ __forceinline__ void gload_lds16(const void* g, void* l) {
  __builtin_amdgcn_global_load_lds(
      (const __attribute__((address_space(1))) unsigned int*)g,
      (__attribute__((address_space(3))) unsigned int*)l, 16, 0, 0);
}

// ---- fp32 -> f16 conversion; q gets (1/0.07)*log2(e) folded in -------------
__global__ void cvt_kernel(const float* __restrict__ q, const float* __restrict__ k,
                           _Float16* __restrict__ qh, _Float16* __restrict__ kh) {
  const float QS = 20.60992915555663f;  // (1/0.07) * log2(e)
  int i = blockIdx.x * 256 + threadIdx.x;
  float4 qv = ((const float4*)q)[i];
  float4 kv = ((const float4*)k)[i];
  half4 qo, ko;
  qo[0] = (_Float16)(qv.x * QS); qo[1] = (_Float16)(qv.y * QS);
  qo[2] = (_Float16)(qv.z * QS); qo[3] = (_Float16)(qv.w * QS);
  ko[0] = (_Float16)kv.x; ko[1] = (_Float16)kv.y;
  ko[2] = (_Float16)kv.z; ko[3] = (_Float16)kv.w;
  ((half4*)qh)[i] = qo;
  ((half4*)kh)[i] = ko;
}

// ---- main fused GEMM + per-lane online base-2 logsumexp --------------------
// Block: 256 threads = 4 waves; wave w owns 16 rows. A-fragments (q) live in
// registers for the whole kernel. k-tile (64x256 f16 = 32 KiB) staged to LDS
// with global_load_lds; 16B chunks XOR-swizzled by row (0 bank conflicts).
// Each lane keeps (M,S) over only the columns IT holds (acc[cf][r], col =
// cf*16+l15); the 16-lane butterfly merge runs once after the tile loop.
__launch_bounds__(256, 4)
__global__ void sim_lse_kernel(const _Float16* __restrict__ qh,
                               const _Float16* __restrict__ kh,
                               float* __restrict__ pM,
                               float* __restrict__ pS,
                               float* __restrict__ pP) {
  __shared__ __align__(16) _Float16 kt[BN * C_DIM];  // 32 KiB
  const int tid  = threadIdx.x;
  const int lane = tid & 63;
  const int wave = tid >> 6;
  const int l15  = lane & 15;
  const int lg   = lane >> 4;       // quad group 0..3

  const int rb   = blockIdx.x;      // row block 0..127
  const int sp   = blockIdx.y;      // column split 0..7
  const int row0 = rb * BM + wave * 16;

  // A fragments: lane holds q[row0+l15][f*32 + lg*8 .. +8)
  half8 afrag[8];
  {
    const _Float16* qr = qh + (size_t)(row0 + l15) * C_DIM + lg * 8;
#pragma unroll
    for (int f = 0; f < 8; ++f)
      afrag[f] = *(const half8*)(qr + f * 32);
  }

  // Per-lane state, rows row0 + lg*4 + r, columns {cf*16+l15 : cf, per tile}
  float M[4], S[4], P[4];
#pragma unroll
  for (int r = 0; r < 4; ++r) { M[r] = -__builtin_inff(); S[r] = 0.f; P[r] = -__builtin_inff(); }

  // swizzled LDS base per col-frag: addr = bbase[cf] ^ (ks*64)
  int bbase[4];
#pragma unroll
  for (int cf = 0; cf < 4; ++cf) {
    int nl = cf * 16 + l15;
    bbase[cf] = nl * 512 + (((nl & 31) * 16) ^ (lg * 16));
  }

  const char* ksrc = (const char*)(kh + (size_t)sp * JCOLS * C_DIM);
  char* lds = (char*)kt;

  for (int jt = 0; jt < JTILES; ++jt) {
    // ---- stage k rows [j0, j0+64) : contiguous 32 KiB, swizzled dest ------
    const char* src = ksrc + (size_t)jt * (BN * C_DIM * 2);
#pragma unroll
    for (int it = 0; it < 8; ++it) {
      int linear = it * 4096 + tid * 16;
      int row = linear >> 9;          // 512 B per k row
      int c16 = (linear >> 4) & 31;   // 16B chunk within row
      int gc  = c16 ^ (row & 31);     // LDS(row,c) holds global(row, c^row)
      gload_lds16(src + row * 512 + gc * 16, lds + linear);
    }
    __syncthreads();

    // ---- 64x64 tile: 8 K-steps x 4 col-frags of 16x16x32 MFMA -------------
    f32x4 acc[4];
#pragma unroll
    for (int cf = 0; cf < 4; ++cf) { f32x4 z = {0.f, 0.f, 0.f, 0.f}; acc[cf] = z; }

#pragma unroll
    for (int ks = 0; ks < 8; ++ks) {
#pragma unroll
      for (int cf = 0; cf < 4; ++cf) {
        half8 b = *(const half8*)(lds + (bbase[cf] ^ (ks * 64)));
        acc[cf] = __builtin_amdgcn_mfma_f32_16x16x32_f16(afrag[ks], b, acc[cf], 0, 0, 0);
      }
    }
    __syncthreads();  // all waves done reading before next staging

    const int j0 = sp * JCOLS + jt * BN;

    // ---- diagonal capture (wave-uniform branch; at most 1 tile/split) -----
    if (row0 >= j0 && row0 < j0 + BN) {
#pragma unroll
      for (int r = 0; r < 4; ++r) {
        int d = row0 - j0 + lg * 4 + r;       // tile-local column of this row's diag
#pragma unroll
        for (int cf = 0; cf < 4; ++cf)
          if (cf * 16 + l15 == d) P[r] = acc[cf][r];
      }
    }

    // ---- per-lane online logsumexp (base 2), no cross-lane traffic --------
#pragma unroll
    for (int r = 0; r < 4; ++r) {
      float v0 = acc[0][r], v1 = acc[1][r], v2 = acc[2][r], v3 = acc[3][r];
      float tmax = fmaxf(fmaxf(v0, v1), fmaxf(v2, v3));
      float newM  = fmaxf(M[r], tmax);
      float alpha = EXP2(M[r] - newM);        // exp2(-inf)=0 handles init
      float p = EXP2(v0 - newM) + EXP2(v1 - newM) +
                EXP2(v2 - newM) + EXP2(v3 - newM);
      S[r] = fmaf(S[r], alpha, p);
      M[r] = newM;
    }
  }

  // ---- one-time 16-lane butterfly merge of (M,S) and max-merge of P -------
#pragma unroll
  for (int r = 0; r < 4; ++r) {
#pragma unroll
    for (int off = 1; off < 16; off <<= 1) {
      float Mo = __shfl_xor(M[r], off);
      float So = __shfl_xor(S[r], off);
      float nm = fmaxf(M[r], Mo);
      S[r] = S[r] * EXP2(M[r] - nm) + So * EXP2(Mo - nm);
      M[r] = nm;
      P[r] = fmaxf(P[r], __shfl_xor(P[r], off));
    }
  }

  if (l15 == 0) {
#pragma unroll
    for (int r = 0; r < 4; ++r) {
      int grow = row0 + lg * 4 + r;
      pM[(size_t)sp * N_ROWS + grow] = M[r];
      pS[(size_t)sp * N_ROWS + grow] = S[r];
      pP[(size_t)sp * N_ROWS + grow] = P[r];
    }
  }
}

// ---- stage 1: 32 blocks, one thread per row; partial sums -----------------
__global__ void finish1_kernel(const float* __restrict__ pM, const float* __restrict__ pS,
                               const float* __restrict__ pP, float* __restrict__ pPart) {
  const int tid = threadIdx.x;
  const int r = blockIdx.x * 256 + tid;
  float m = -__builtin_inff();
#pragma unroll
  for (int s = 0; s < SPLIT; ++s) m = fmaxf(m, pM[s * N_ROWS + r]);
  float ssum = 0.f;
  float pos  = -__builtin_inff();
#pragma unroll
  for (int s = 0; s < SPLIT; ++s) {
    ssum = fmaf(pS[s * N_ROWS + r], EXP2(pM[s * N_ROWS + r] - m), ssum);
    pos = fmaxf(pos, pP[s * N_ROWS + r]);
  }
  float accl = (m + LOG2(ssum)) - pos;   // row loss in base-2 units
#pragma unroll
  for (int off = 1; off < 64; off <<= 1) accl += __shfl_xor(accl, off);
  __shared__ float wsum[4];
  if ((tid & 63) == 0) wsum[tid >> 6] = accl;
  __syncthreads();
  if (tid == 0)
    pPart[blockIdx.x] = wsum[0] + wsum[1] + wsum[2] + wsum[3];
}

// ---- stage 2: reduce 32 partials, convert base-2 -> nats, mean ------------
__global__ void finish2_kernel(const float* __restrict__ pPart, float* __restrict__ out) {
  const int tid = threadIdx.x;   // 64 threads
  float v = (tid < 32) ? pPart[tid] : 0.f;
#pragma unroll
  for (int off = 1; off < 64; off <<= 1) v += __shfl_xor(v, off);
  if (tid == 0)
    out[0] = v * (0.69314718055994531f / (float)N_ROWS);  // ln2 * mean
}

extern "C" void kernel_launch(void* const* d_in, const int* in_sizes, int n_in,
                              void* d_out, int out_size, void* d_ws, size_t ws_size,
                              hipStream_t stream) {
  const float* q = (const float*)d_in[0];
  const float* k = (const float*)d_in[1];
  float* out = (float*)d_out;
  char* ws = (char*)d_ws;

  _Float16* qh = (_Float16*)ws;                                  // 4 MiB
  _Float16* kh = (_Float16*)(ws + (size_t)N_ROWS * C_DIM * 2);   // 4 MiB
  float* pM = (float*)(ws + (size_t)N_ROWS * C_DIM * 4);         // 256 KiB each
  float* pS = pM + SPLIT * N_ROWS;
  float* pP = pS + SPLIT * N_ROWS;
  float* pPart = pP + SPLIT * N_ROWS;                            // 32 floats

  cvt_kernel<<<dim3(N_ROWS * C_DIM / 4 / 256), dim3(256), 0, stream>>>(q, k, qh, kh);
  sim_lse_kernel<<<dim3(N_ROWS / BM, SPLIT), dim3(256), 0, stream>>>(qh, kh, pM, pS, pP);
  finish1_kernel<<<dim3(N_ROWS / 256), dim3(256), 0, stream>>>(pM, pS, pP, pPart);
  finish2_kernel<<<dim3(1), dim3(64), 0, stream>>>(pPart, out);
}